// Round 2
// baseline (423.178 us; speedup 1.0000x reference)
//
#include <hip/hip_runtime.h>
#include <cstdint>
#include <cstddef>

#define T_TOK 2048
#define DMODEL 1024
#define NEXP 8
#define HID 2048
#define DUMP_ID 4096   // assignment-id for padding rows (token row 2048 = zeros)
#define BRS 40         // padded LDS row stride (halves) for B tiles: 80B -> bank+20/row

typedef __bf16 bf16x8 __attribute__((ext_vector_type(8)));
typedef float f32x4 __attribute__((ext_vector_type(4)));
typedef unsigned short u16;
typedef u16 u16x8 __attribute__((ext_vector_type(8)));

__device__ __forceinline__ u16 f2bf(float f) {
    union { float f; unsigned int u; } v; v.f = f;
    unsigned int u = v.u;
    unsigned int r = (u + 0x7FFFu + ((u >> 16) & 1u)) >> 16;  // RNE
    return (u16)r;
}

__device__ __forceinline__ void gl2lds16(const void* g, void* l) {
    __builtin_amdgcn_global_load_lds(
        (const __attribute__((address_space(1))) void*)g,
        (__attribute__((address_space(3))) void*)l,
        16, 0, 0);
}

// ---------------------------------------------------------------- init ------
__global__ void init_k(int* __restrict__ counts, int* __restrict__ list,
                       unsigned short* __restrict__ xb_dump_row) {
    int i = blockIdx.x * blockDim.x + threadIdx.x;
    if (i < NEXP) counts[i] = 0;
    if (i < NEXP * T_TOK) list[i] = DUMP_ID;
    if (i < DMODEL) xb_dump_row[i] = 0;  // zero token row used by padded slots
}

// -------------------------------------------------------------- router ------
// one wave per token: fp32 GEMV vs gate_w, sigmoid, top-2 (ties -> lowest idx,
// matching lax.top_k), atomic slot assignment; also converts x row to bf16.
__global__ __launch_bounds__(64) void router_k(
    const float* __restrict__ x, const float* __restrict__ gw,
    const float* __restrict__ bias, unsigned short* __restrict__ xb,
    int* __restrict__ counts, int* __restrict__ list, float* __restrict__ w2) {
    const int t = blockIdx.x;
    const int lane = threadIdx.x;
    const float* xr = x + (size_t)t * DMODEL;
    float acc[NEXP];
#pragma unroll
    for (int e = 0; e < NEXP; ++e) acc[e] = 0.f;
#pragma unroll
    for (int j = 0; j < DMODEL / 64; ++j) {
        int i = lane + j * 64;
        float xv = xr[i];
        xb[(size_t)t * DMODEL + i] = f2bf(xv);
#pragma unroll
        for (int e = 0; e < NEXP; ++e) acc[e] += xv * gw[e * DMODEL + i];
    }
#pragma unroll
    for (int e = 0; e < NEXP; ++e)
        for (int off = 32; off > 0; off >>= 1) acc[e] += __shfl_xor(acc[e], off, 64);
    if (lane == 0) {
        float sc[NEXP], bi[NEXP];
#pragma unroll
        for (int e = 0; e < NEXP; ++e) {
            sc[e] = 1.f / (1.f + expf(-acc[e]));
            bi[e] = sc[e] + bias[e];
        }
        int e0 = 0;
        for (int e = 1; e < NEXP; ++e) if (bi[e] > bi[e0]) e0 = e;
        int e1 = -1;
        for (int e = 0; e < NEXP; ++e) {
            if (e == e0) continue;
            if (e1 < 0 || bi[e] > bi[e1]) e1 = e;
        }
        int s0 = atomicAdd(&counts[e0], 1);
        list[e0 * T_TOK + s0] = 2 * t;
        int s1 = atomicAdd(&counts[e1], 1);
        list[e1 * T_TOK + s1] = 2 * t + 1;
        w2[2 * t]     = sc[e0] * sc[e0];
        w2[2 * t + 1] = sc[e1] * sc[e1];
    }
}

// ---------------------------------------------------- grouped GEMM ----------
// MODE 0 (up):   A = xb gathered (row = id>>1, K=1024), B = w_up[e] fp32 (2048 x K)
//                epilogue: h[id][n] = bf16( w2[id] * relu(v)^2 )
// MODE 1 (down): A = h gathered (row = id, K=2048),    B = w_down[e] fp32 (1024 x K)
//                epilogue: c[id][n] = v (fp32)
// 128x128 tile, BK=32, double-buffered LDS, ONE barrier/iter.
// B is converted fp32->bf16 in-flight during staging (convert_w pass removed).
template <int MODE>
__global__ __launch_bounds__(256, 2) void moe_gemm(
    const u16* __restrict__ Asrc, const int* __restrict__ list,
    const int* __restrict__ counts, const float* __restrict__ Ballf,
    const float* __restrict__ w2, u16* __restrict__ Hout,
    float* __restrict__ Cout) {
    constexpr int K = (MODE == 0) ? DMODEL : HID;
    constexpr int NK = K / 32;
    const int e = blockIdx.z;
    const int m0 = blockIdx.y * 128;
    if (m0 >= counts[e]) return;
    const int n0 = blockIdx.x * 128;
    const int tid = threadIdx.x;
    const int lane = tid & 63;
    const int w = tid >> 6;

    __shared__ u16 As[2][128 * 32];    // A: global_load_lds layout (unpadded)
    __shared__ u16 Bs[2][128 * BRS];   // B: manual staging, padded rows

    const int* mylist = list + e * T_TOK + m0;
    const float* Bf = Ballf + (size_t)e * HID * DMODEL;

    // A staging source pointers (gather via list)
    const u16* ap[2];
#pragma unroll
    for (int it = 0; it < 2; ++it) {
        int seg = it * 256 + tid;
        int row = seg >> 2;
        int ks = (seg & 3) * 8;
        int id = mylist[row];
        int arow = (MODE == 0) ? (id >> 1) : id;
        ap[it] = Asrc + (size_t)arow * K + ks;
    }
    // B staging: each thread stages 16 consecutive fp32 of one row
    const int brow = tid >> 1;
    const int bkh = (tid & 1) * 16;
    const float* bp = Bf + (size_t)(n0 + brow) * K + bkh;
    u16* bdst0 = &Bs[0][0] + brow * BRS + bkh;

    const int wm = (w >> 1) * 64;
    const int wn = (w & 1) * 64;
    const int quad = lane >> 4;
    const int lrow = lane & 15;

    f32x4 acc[4][4];
#pragma unroll
    for (int i = 0; i < 4; ++i)
#pragma unroll
        for (int j = 0; j < 4; ++j) acc[i][j] = f32x4{0.f, 0.f, 0.f, 0.f};

    // ---- prologue: stage k-tile 0 into buffer 0
#pragma unroll
    for (int it = 0; it < 2; ++it)
        gl2lds16(ap[it], &As[0][(it * 256 + w * 64) * 8]);
    {
        const float4* s = (const float4*)bp;
        float4 f0 = s[0], f1 = s[1], f2 = s[2], f3 = s[3];
        u16x8 lo = {f2bf(f0.x), f2bf(f0.y), f2bf(f0.z), f2bf(f0.w),
                    f2bf(f1.x), f2bf(f1.y), f2bf(f1.z), f2bf(f1.w)};
        u16x8 hi = {f2bf(f2.x), f2bf(f2.y), f2bf(f2.z), f2bf(f2.w),
                    f2bf(f3.x), f2bf(f3.y), f2bf(f3.z), f2bf(f3.w)};
        *(u16x8*)bdst0 = lo;
        *(u16x8*)(bdst0 + 8) = hi;
    }

    // ---- pipelined K loop
    for (int kt = 0; kt < NK; ++kt) {
        const int cur = kt & 1;
        const int nxt = cur ^ 1;
        __syncthreads();  // drains stage(kt); also fences buffer reuse
        float4 f0, f1, f2, f3;
        const bool more = (kt + 1 < NK);
        if (more) {
            const float4* s = (const float4*)(bp + (kt + 1) * 32);
            f0 = s[0]; f1 = s[1]; f2 = s[2]; f3 = s[3];
#pragma unroll
            for (int it = 0; it < 2; ++it)
                gl2lds16(ap[it] + (kt + 1) * 32, &As[nxt][(it * 256 + w * 64) * 8]);
        }
        bf16x8 af[4], bfr[4];
#pragma unroll
        for (int i = 0; i < 4; ++i) {
            af[i]  = *(const bf16x8*)&As[cur][(wm + i * 16 + lrow) * 32 + quad * 8];
            bfr[i] = *(const bf16x8*)&Bs[cur][(wn + i * 16 + lrow) * BRS + quad * 8];
        }
#pragma unroll
        for (int i = 0; i < 4; ++i)
#pragma unroll
            for (int j = 0; j < 4; ++j)
                acc[i][j] = __builtin_amdgcn_mfma_f32_16x16x32_bf16(af[i], bfr[j],
                                                                    acc[i][j], 0, 0, 0);
        if (more) {  // convert + store B(kt+1) after compute (loads had time to land)
            u16* d = bdst0 + nxt * (128 * BRS);
            u16x8 lo = {f2bf(f0.x), f2bf(f0.y), f2bf(f0.z), f2bf(f0.w),
                        f2bf(f1.x), f2bf(f1.y), f2bf(f1.z), f2bf(f1.w)};
            u16x8 hi = {f2bf(f2.x), f2bf(f2.y), f2bf(f2.z), f2bf(f2.w),
                        f2bf(f3.x), f2bf(f3.y), f2bf(f3.z), f2bf(f3.w)};
            *(u16x8*)d = lo;
            *(u16x8*)(d + 8) = hi;
        }
    }

    // ---- epilogue: C/D mapping col = lane&15, row = (lane>>4)*4 + reg
#pragma unroll
    for (int i = 0; i < 4; ++i) {
        int mbase = wm + i * 16 + (lane >> 4) * 4;
        int ids[4];
        float ww[4];
#pragma unroll
        for (int r = 0; r < 4; ++r) {
            ids[r] = mylist[mbase + r];
            if (MODE == 0) ww[r] = w2[ids[r]];
        }
#pragma unroll
        for (int j = 0; j < 4; ++j) {
            int n = n0 + wn + j * 16 + (lane & 15);
#pragma unroll
            for (int r = 0; r < 4; ++r) {
                float v = acc[i][j][r];
                if (MODE == 0) {
                    v = (v > 0.f) ? v * v * ww[r] : 0.f;
                    Hout[(size_t)ids[r] * HID + n] = f2bf(v);
                } else {
                    Cout[(size_t)ids[r] * DMODEL + n] = v;
                }
            }
        }
    }
}

// -------------------------------------------------------------- combine -----
__global__ void combine_k(const float4* __restrict__ c, float4* __restrict__ out) {
    int i = blockIdx.x * blockDim.x + threadIdx.x;  // over T*1024/4
    if (i >= T_TOK * (DMODEL / 4)) return;
    int t = i >> 8;  // 256 float4 per row
    int d = i & 255;
    float4 a = c[(size_t)(2 * t) * (DMODEL / 4) + d];
    float4 b = c[(size_t)(2 * t + 1) * (DMODEL / 4) + d];
    float4 o;
    o.x = a.x + b.x; o.y = a.y + b.y; o.z = a.z + b.z; o.w = a.w + b.w;
    out[i] = o;
}

// ---------------------------------------------------------------------------
extern "C" void kernel_launch(void* const* d_in, const int* in_sizes, int n_in,
                              void* d_out, int out_size, void* d_ws, size_t ws_size,
                              hipStream_t stream) {
    const float* x      = (const float*)d_in[0];
    const float* gate_w = (const float*)d_in[1];
    const float* w_up   = (const float*)d_in[2];
    const float* w_down = (const float*)d_in[3];
    const float* bias   = (const float*)d_in[4];
    float* out = (float*)d_out;

    // workspace layout (all chunks 16B-aligned)
    char* p = (char*)d_ws;
    int* counts = (int*)p;              p += 256;
    int* list   = (int*)p;              p += NEXP * T_TOK * 4;          // 64 KB
    float* w2   = (float*)p;            p += 4104 * 4;                  // 4097 used
    unsigned short* xb = (unsigned short*)p;  p += (size_t)(T_TOK + 1) * DMODEL * 2;
    unsigned short* h  = (unsigned short*)p;  p += (size_t)(2 * T_TOK + 1) * HID * 2;
    float* c           = (float*)p;           p += (size_t)(2 * T_TOK + 1) * DMODEL * 4;

    // 1. init counters / DUMP lists / zero dump token row
    init_k<<<64, 256, 0, stream>>>(counts, list, xb + (size_t)T_TOK * DMODEL);

    // 2. router (+ x -> bf16)
    router_k<<<T_TOK, 64, 0, stream>>>(x, gate_w, bias, xb, counts, list, w2);

    // 3. up-GEMM: h = bf16( w2 * relu(x @ Wu^T)^2 )   (fp32 weights staged in-kernel)
    moe_gemm<0><<<dim3(HID / 128, 16, NEXP), 256, 0, stream>>>(
        xb, list, counts, w_up, w2, h, nullptr);

    // 4. down-GEMM: c[id] = h[id] @ Wd^T
    moe_gemm<1><<<dim3(DMODEL / 128, 16, NEXP), 256, 0, stream>>>(
        h, list, counts, w_down, w2, nullptr, c);

    // 5. combine the two assignments per token
    combine_k<<<(T_TOK * (DMODEL / 4) + 255) / 256, 256, 0, stream>>>(
        (const float4*)c, (float4*)out);
}

// Round 3
// 299.496 us; speedup vs baseline: 1.4130x; 1.4130x over previous
//
#include <hip/hip_runtime.h>
#include <cstdint>
#include <cstddef>

#define T_TOK 2048
#define DMODEL 1024
#define NEXP 8
#define HID 2048
#define DUMP_ID 4096   // assignment-id for padding rows (token row 2048 = zeros)

typedef __bf16 bf16x8 __attribute__((ext_vector_type(8)));
typedef float f32x4 __attribute__((ext_vector_type(4)));
typedef unsigned short u16;
typedef u16 u16x8 __attribute__((ext_vector_type(8)));

__device__ __forceinline__ u16 f2bf(float f) {
    union { float f; unsigned int u; } v; v.f = f;
    unsigned int u = v.u;
    unsigned int r = (u + 0x7FFFu + ((u >> 16) & 1u)) >> 16;  // RNE
    return (u16)r;
}

__device__ __forceinline__ void gl2lds16(const void* g, void* l) {
    __builtin_amdgcn_global_load_lds(
        (const __attribute__((address_space(1))) void*)g,
        (__attribute__((address_space(3))) void*)l,
        16, 0, 0);
}

// ---------------------------------------------------------------- init ------
__global__ void init_k(int* __restrict__ counts, int* __restrict__ list,
                       unsigned short* __restrict__ xb_dump_row) {
    int i = blockIdx.x * blockDim.x + threadIdx.x;
    if (i < NEXP) counts[i] = 0;
    if (i < NEXP * T_TOK) list[i] = DUMP_ID;
    if (i < DMODEL) xb_dump_row[i] = 0;  // zero token row used by padded slots
}

// -------------------------------------------------------------- router ------
__global__ __launch_bounds__(64) void router_k(
    const float* __restrict__ x, const float* __restrict__ gw,
    const float* __restrict__ bias, unsigned short* __restrict__ xb,
    int* __restrict__ counts, int* __restrict__ list, float* __restrict__ w2) {
    const int t = blockIdx.x;
    const int lane = threadIdx.x;
    const float* xr = x + (size_t)t * DMODEL;
    float acc[NEXP];
#pragma unroll
    for (int e = 0; e < NEXP; ++e) acc[e] = 0.f;
#pragma unroll
    for (int j = 0; j < DMODEL / 64; ++j) {
        int i = lane + j * 64;
        float xv = xr[i];
        xb[(size_t)t * DMODEL + i] = f2bf(xv);
#pragma unroll
        for (int e = 0; e < NEXP; ++e) acc[e] += xv * gw[e * DMODEL + i];
    }
#pragma unroll
    for (int e = 0; e < NEXP; ++e)
        for (int off = 32; off > 0; off >>= 1) acc[e] += __shfl_xor(acc[e], off, 64);
    if (lane == 0) {
        float sc[NEXP], bi[NEXP];
#pragma unroll
        for (int e = 0; e < NEXP; ++e) {
            sc[e] = 1.f / (1.f + expf(-acc[e]));
            bi[e] = sc[e] + bias[e];
        }
        int e0 = 0;
        for (int e = 1; e < NEXP; ++e) if (bi[e] > bi[e0]) e0 = e;  // ties -> lowest
        int e1 = -1;
        for (int e = 0; e < NEXP; ++e) {
            if (e == e0) continue;
            if (e1 < 0 || bi[e] > bi[e1]) e1 = e;
        }
        int s0 = atomicAdd(&counts[e0], 1);
        list[e0 * T_TOK + s0] = 2 * t;
        int s1 = atomicAdd(&counts[e1], 1);
        list[e1 * T_TOK + s1] = 2 * t + 1;
        w2[2 * t]     = sc[e0] * sc[e0];
        w2[2 * t + 1] = sc[e1] * sc[e1];
    }
}

// ------------------------------------------------- weight fp32 -> bf16 ------
// one thread = 8 floats: 2x float4 load, 1x 16B store
__global__ void convert_w(const float4* __restrict__ wu, const float4* __restrict__ wd,
                          u16x8* __restrict__ wub, u16x8* __restrict__ wdb, int n8) {
    int i = blockIdx.x * blockDim.x + threadIdx.x;
    const float4* src; u16x8* dst; int idx;
    if (i < n8) { src = wu; dst = wub; idx = i; }
    else        { src = wd; dst = wdb; idx = i - n8; }
    float4 a = src[2 * idx], b = src[2 * idx + 1];
    u16x8 o = {f2bf(a.x), f2bf(a.y), f2bf(a.z), f2bf(a.w),
               f2bf(b.x), f2bf(b.y), f2bf(b.z), f2bf(b.w)};
    dst[idx] = o;
}

// ---------------------------------------------------- grouped GEMM ----------
// MODE 0 (up):   A = xb gathered (row = id>>1, K=1024), B = wub[e] (2048 x K)
//                epilogue: h[id][n] = bf16( w2[id] * relu(v)^2 )
// MODE 1 (down): A = h gathered (row = id, K=2048),    B = wdb[e] (1024 x K)
//                epilogue: c[id][n] = v (fp32)
// 128x128 tile, BK=64, single LDS buffer, global_load_lds staging with XOR
// swizzle (chunk g ^ (row&7)) so ds_read_b128 is bank-balanced.
// 1D grid: b -> e = b&7 (XCD round-robin), rest = b>>3, n = rest & (NTN-1),
// m = rest >> log2(NTN): active blocks form a dense prefix spread over all CUs.
template <int MODE>
__global__ __launch_bounds__(256, 2) void moe_gemm(
    const u16* __restrict__ Asrc, const int* __restrict__ list,
    const int* __restrict__ counts, const u16* __restrict__ Ball,
    const float* __restrict__ w2, u16* __restrict__ Hout,
    float* __restrict__ Cout) {
    constexpr int K   = (MODE == 0) ? DMODEL : HID;   // 1024 / 2048
    constexpr int N   = (MODE == 0) ? HID : DMODEL;   // 2048 / 1024
    constexpr int NKT = K / 64;                       // 16 / 32
    constexpr int NTN = N / 128;                      // 16 / 8
    constexpr int LOGNTN = (MODE == 0) ? 4 : 3;

    const int b = blockIdx.x;
    const int e = b & 7;
    const int rest = b >> 3;
    const int m0 = (rest >> LOGNTN) * 128;
    if (m0 >= counts[e]) return;
    const int n0 = (rest & (NTN - 1)) * 128;

    const int tid = threadIdx.x;
    const int lane = tid & 63;
    const int w = tid >> 6;

    __shared__ u16 As[128 * 64];
    __shared__ u16 Bs[128 * 64];

    const int* mylist = list + e * T_TOK + m0;
    const u16* B = Ball + (size_t)e * HID * DMODEL;

    // staging pointers: 4 instrs each for A and B; seg = it*256+tid,
    // row = seg>>3, chunk g = tid&7, swizzled source chunk gs = g ^ (row&7)
    const u16* ap[4];
    const u16* bp[4];
#pragma unroll
    for (int it = 0; it < 4; ++it) {
        int row = it * 32 + (tid >> 3);
        int gs = (tid & 7) ^ (row & 7);
        int id = mylist[row];
        int arow = (MODE == 0) ? (id >> 1) : id;
        ap[it] = Asrc + (size_t)arow * K + gs * 8;
        bp[it] = B + (size_t)(n0 + row) * K + gs * 8;
    }

    const int wm = (w >> 1) * 64;
    const int wn = (w & 1) * 64;
    const int quad = lane >> 4;
    const int lrow = lane & 15;

    f32x4 acc[4][4];
#pragma unroll
    for (int i = 0; i < 4; ++i)
#pragma unroll
        for (int j = 0; j < 4; ++j) acc[i][j] = f32x4{0.f, 0.f, 0.f, 0.f};

    for (int kt = 0; kt < NKT; ++kt) {
#pragma unroll
        for (int it = 0; it < 4; ++it)
            gl2lds16(ap[it] + kt * 64, &As[(it * 256 + w * 64) * 8]);
#pragma unroll
        for (int it = 0; it < 4; ++it)
            gl2lds16(bp[it] + kt * 64, &Bs[(it * 256 + w * 64) * 8]);
        __syncthreads();  // drain staging
#pragma unroll
        for (int s = 0; s < 2; ++s) {
            const int q = s * 4 + quad;
            bf16x8 af[4], bfr[4];
#pragma unroll
            for (int i = 0; i < 4; ++i) {
                int ra = wm + i * 16 + lrow;
                int rb = wn + i * 16 + lrow;
                af[i]  = *(const bf16x8*)&As[ra * 64 + (q ^ (ra & 7)) * 8];
                bfr[i] = *(const bf16x8*)&Bs[rb * 64 + (q ^ (rb & 7)) * 8];
            }
#pragma unroll
            for (int i = 0; i < 4; ++i)
#pragma unroll
                for (int j = 0; j < 4; ++j)
                    acc[i][j] = __builtin_amdgcn_mfma_f32_16x16x32_bf16(
                        af[i], bfr[j], acc[i][j], 0, 0, 0);
        }
        __syncthreads();  // protect LDS before next stage
    }

    // epilogue: C/D mapping col = lane&15, row = (lane>>4)*4 + reg
#pragma unroll
    for (int i = 0; i < 4; ++i) {
        int mbase = wm + i * 16 + (lane >> 4) * 4;
        int ids[4];
        float ww[4];
#pragma unroll
        for (int r = 0; r < 4; ++r) {
            ids[r] = mylist[mbase + r];
            if (MODE == 0) ww[r] = w2[ids[r]];
        }
#pragma unroll
        for (int j = 0; j < 4; ++j) {
            int n = n0 + wn + j * 16 + (lane & 15);
#pragma unroll
            for (int r = 0; r < 4; ++r) {
                float v = acc[i][j][r];
                if (MODE == 0) {
                    v = (v > 0.f) ? v * v * ww[r] : 0.f;
                    Hout[(size_t)ids[r] * HID + n] = f2bf(v);
                } else {
                    Cout[(size_t)ids[r] * DMODEL + n] = v;
                }
            }
        }
    }
}

// -------------------------------------------------------------- combine -----
__global__ void combine_k(const float4* __restrict__ c, float4* __restrict__ out) {
    int i = blockIdx.x * blockDim.x + threadIdx.x;  // over T*1024/4
    if (i >= T_TOK * (DMODEL / 4)) return;
    int t = i >> 8;
    int d = i & 255;
    float4 a = c[(size_t)(2 * t) * (DMODEL / 4) + d];
    float4 b = c[(size_t)(2 * t + 1) * (DMODEL / 4) + d];
    float4 o;
    o.x = a.x + b.x; o.y = a.y + b.y; o.z = a.z + b.z; o.w = a.w + b.w;
    out[i] = o;
}

// ---------------------------------------------------------------------------
extern "C" void kernel_launch(void* const* d_in, const int* in_sizes, int n_in,
                              void* d_out, int out_size, void* d_ws, size_t ws_size,
                              hipStream_t stream) {
    const float* x      = (const float*)d_in[0];
    const float* gate_w = (const float*)d_in[1];
    const float* w_up   = (const float*)d_in[2];
    const float* w_down = (const float*)d_in[3];
    const float* bias   = (const float*)d_in[4];
    float* out = (float*)d_out;

    // workspace layout (16B aligned chunks)
    char* p = (char*)d_ws;
    int* counts = (int*)p;              p += 256;
    int* list   = (int*)p;              p += NEXP * T_TOK * 4;
    float* w2   = (float*)p;            p += 4104 * 4;
    u16* xb  = (u16*)p;  p += (size_t)(T_TOK + 1) * DMODEL * 2;
    u16* wub = (u16*)p;  p += (size_t)NEXP * HID * DMODEL * 2;
    u16* wdb = (u16*)p;  p += (size_t)NEXP * HID * DMODEL * 2;
    u16* h   = (u16*)p;  p += (size_t)(2 * T_TOK + 1) * HID * 2;
    float* c = (float*)p; p += (size_t)(2 * T_TOK + 1) * DMODEL * 4;

    // 1. init counters / DUMP lists / zero dump token row
    init_k<<<64, 256, 0, stream>>>(counts, list, xb + (size_t)T_TOK * DMODEL);

    // 2. router (+ x -> bf16)
    router_k<<<T_TOK, 64, 0, stream>>>(x, gate_w, bias, xb, counts, list, w2);

    // 3. weights -> bf16 (n8 = elements/8 per tensor)
    {
        int n8 = NEXP * HID * DMODEL / 8;
        convert_w<<<(2 * n8) / 256, 256, 0, stream>>>(
            (const float4*)w_up, (const float4*)w_down,
            (u16x8*)wub, (u16x8*)wdb, n8);
    }

    // 4. up-GEMM: h = bf16( w2 * relu(x @ Wu^T)^2 )
    moe_gemm<0><<<16 * (HID / 128) * NEXP, 256, 0, stream>>>(
        xb, list, counts, wub, w2, h, nullptr);

    // 5. down-GEMM: c[id] = h[id] @ Wd^T
    moe_gemm<1><<<16 * (DMODEL / 128) * NEXP, 256, 0, stream>>>(
        h, list, counts, wdb, w2, nullptr, c);

    // 6. combine
    combine_k<<<(T_TOK * (DMODEL / 4) + 255) / 256, 256, 0, stream>>>(
        (const float4*)c, (float4*)out);
}

// Round 4
// 264.711 us; speedup vs baseline: 1.5986x; 1.1314x over previous
//
#include <hip/hip_runtime.h>
#include <cstdint>
#include <cstddef>

#define T_TOK 2048
#define DMODEL 1024
#define NEXP 8
#define HID 2048
#define DUMP_ID 4096   // assignment-id for padding rows (token row 2048 = zeros)
#define NB_CONV 8192   // conversion blocks in fused_pre (x4 float4 per thread)

typedef __bf16 bf16x8 __attribute__((ext_vector_type(8)));
typedef float f32x4 __attribute__((ext_vector_type(4)));
typedef unsigned short u16;
typedef u16 u16x8 __attribute__((ext_vector_type(8)));

__device__ __forceinline__ u16 f2bf(float f) {
    union { float f; unsigned int u; } v; v.f = f;
    unsigned int u = v.u;
    unsigned int r = (u + 0x7FFFu + ((u >> 16) & 1u)) >> 16;  // RNE
    return (u16)r;
}

__device__ __forceinline__ void gl2lds16(const void* g, void* l) {
    __builtin_amdgcn_global_load_lds(
        (const __attribute__((address_space(1))) void*)g,
        (__attribute__((address_space(3))) void*)l,
        16, 0, 0);
}

// ------------------------------------------------------------ fused_pre -----
// blocks [0, NB_CONV)        : weight fp32->bf16 (coalesced float4 -> ushort4)
// blocks [NB_CONV, +256)     : router scores (one wave = 2 tokens, NO atomics)
// block  NB_CONV+256         : zero xb dump row
__global__ __launch_bounds__(256) void fused_pre(
    const float4* __restrict__ wu4, const float4* __restrict__ wd4,
    ushort4* __restrict__ wub4, ushort4* __restrict__ wdb4,
    const float4* __restrict__ x4, const float4* __restrict__ gw4,
    const float* __restrict__ bias, ushort4* __restrict__ xb4,
    unsigned int* __restrict__ selpack, float* __restrict__ w2,
    unsigned int* __restrict__ xb_dump_row_u32) {
    const int b = blockIdx.x;
    const int tid = threadIdx.x;

    if (b < NB_CONV) {                       // ---- weight conversion ----
        const int n4u = NEXP * HID * DMODEL / 4;     // 4,194,304 float4 per tensor
        int i0 = b * 256 + tid;
#pragma unroll
        for (int c = 0; c < 4; ++c) {
            int idx = i0 + c * (NB_CONV * 256);
            float4 f = (idx < n4u) ? wu4[idx] : wd4[idx - n4u];
            ushort4 o;
            o.x = f2bf(f.x); o.y = f2bf(f.y); o.z = f2bf(f.z); o.w = f2bf(f.w);
            if (idx < n4u) wub4[idx] = o; else wdb4[idx - n4u] = o;
        }
        return;
    }
    if (b == NB_CONV + 256) {                // ---- zero dump token row ----
        if (tid < DMODEL / 2) xb_dump_row_u32[tid] = 0;
        return;
    }
    // ---- router: wave wv of router-block rb handles tokens 2p, 2p+1 ----
    const int rb = b - NB_CONV;
    const int wv = tid >> 6;
    const int lane = tid & 63;
    const int pair = rb * 4 + wv;            // 0..1023
    const int t0 = 2 * pair, t1 = t0 + 1;

    float acc0[NEXP], acc1[NEXP];
#pragma unroll
    for (int e = 0; e < NEXP; ++e) { acc0[e] = 0.f; acc1[e] = 0.f; }
#pragma unroll
    for (int j = 0; j < 4; ++j) {
        int i4 = lane + j * 64;              // float4 index within row (256/row)
        float4 a0 = x4[t0 * 256 + i4];
        float4 a1 = x4[t1 * 256 + i4];
        ushort4 s0, s1;
        s0.x = f2bf(a0.x); s0.y = f2bf(a0.y); s0.z = f2bf(a0.z); s0.w = f2bf(a0.w);
        s1.x = f2bf(a1.x); s1.y = f2bf(a1.y); s1.z = f2bf(a1.z); s1.w = f2bf(a1.w);
        xb4[t0 * 256 + i4] = s0;
        xb4[t1 * 256 + i4] = s1;
#pragma unroll
        for (int e = 0; e < NEXP; ++e) {
            float4 g = gw4[e * 256 + i4];
            acc0[e] += a0.x * g.x + a0.y * g.y + a0.z * g.z + a0.w * g.w;
            acc1[e] += a1.x * g.x + a1.y * g.y + a1.z * g.z + a1.w * g.w;
        }
    }
#pragma unroll
    for (int e = 0; e < NEXP; ++e)
        for (int off = 32; off > 0; off >>= 1) {
            acc0[e] += __shfl_xor(acc0[e], off, 64);
            acc1[e] += __shfl_xor(acc1[e], off, 64);
        }
    if (lane == 0) {
#pragma unroll
        for (int tt = 0; tt < 2; ++tt) {
            int t = tt ? t1 : t0;
            float sc[NEXP], bi[NEXP];
#pragma unroll
            for (int e = 0; e < NEXP; ++e) {
                float a = tt ? acc1[e] : acc0[e];
                sc[e] = 1.f / (1.f + expf(-a));
                bi[e] = sc[e] + bias[e];
            }
            int e0 = 0;
            for (int e = 1; e < NEXP; ++e) if (bi[e] > bi[e0]) e0 = e;  // ties->lowest
            int e1 = -1;
            for (int e = 0; e < NEXP; ++e) {
                if (e == e0) continue;
                if (e1 < 0 || bi[e] > bi[e1]) e1 = e;
            }
            selpack[t] = (unsigned int)e0 | ((unsigned int)e1 << 8);
            w2[2 * t]     = sc[e0] * sc[e0];
            w2[2 * t + 1] = sc[e1] * sc[e1];
        }
    }
}

// ------------------------------------------------------------ build_lists ---
// 8 blocks (one per expert), 256 threads: deterministic ballot-compaction.
__global__ __launch_bounds__(256) void build_lists(
    const unsigned int* __restrict__ selpack, int* __restrict__ counts,
    int* __restrict__ list) {
    const int e = blockIdx.x;
    const int tid = threadIdx.x;
    const int lane = tid & 63;
    const int wv = tid >> 6;
    __shared__ int wsum[4];
    __shared__ int base;
    if (tid == 0) base = 0;
    __syncthreads();
    for (int tb = 0; tb < T_TOK; tb += 256) {
        int t = tb + tid;
        unsigned int sp = selpack[t];
        bool f1 = ((sp >> 8) & 255u) == (unsigned)e;
        bool f = ((sp & 255u) == (unsigned)e) | f1;
        int id = 2 * t + (f1 ? 1 : 0);
        unsigned long long m = __ballot(f);
        int pos = __popcll(m & ((1ull << lane) - 1ull));
        if (lane == 0) wsum[wv] = __popcll(m);
        __syncthreads();
        int woff = 0;
#pragma unroll
        for (int i = 0; i < 4; ++i) if (i < wv) woff += wsum[i];
        int bse = base;
        if (f) list[e * T_TOK + bse + woff + pos] = id;
        __syncthreads();
        if (tid == 0) base = bse + wsum[0] + wsum[1] + wsum[2] + wsum[3];
    }
    __syncthreads();
    int total = base;
    if (tid == 0) counts[e] = total;
    for (int i = total + tid; i < T_TOK; i += 256) list[e * T_TOK + i] = DUMP_ID;
}

// ---------------------------------------------------- grouped GEMM ----------
// MODE 0 (up):   A = xb gathered (row=id>>1, K=1024), B = wub[e] (2048 x K)
//                epilogue: h[id][n] = bf16( w2[id] * relu(v)^2 )
// MODE 1 (down): A = h gathered (row=id, K=2048),    B = wdb[e] (1024 x K)
//                epilogue: atomicAdd(out[id>>1][n], v)   (combine fused)
// 128x128 tile, BK=64, XOR-swizzled global_load_lds staging.
template <int MODE>
__global__ __launch_bounds__(256, 2) void moe_gemm(
    const u16* __restrict__ Asrc, const int* __restrict__ list,
    const int* __restrict__ counts, const u16* __restrict__ Ball,
    const float* __restrict__ w2, u16* __restrict__ Hout,
    float* __restrict__ Cout) {
    constexpr int K   = (MODE == 0) ? DMODEL : HID;   // 1024 / 2048
    constexpr int N   = (MODE == 0) ? HID : DMODEL;   // 2048 / 1024
    constexpr int NKT = K / 64;                       // 16 / 32
    constexpr int NTN = N / 128;                      // 16 / 8
    constexpr int LOGNTN = (MODE == 0) ? 4 : 3;

    const int b = blockIdx.x;
    const int e = b & 7;
    const int rest = b >> 3;
    const int m0 = (rest >> LOGNTN) * 128;
    if (m0 >= counts[e]) return;
    const int n0 = (rest & (NTN - 1)) * 128;

    const int tid = threadIdx.x;
    const int lane = tid & 63;
    const int w = tid >> 6;

    __shared__ u16 As[128 * 64];
    __shared__ u16 Bs[128 * 64];

    const int* mylist = list + e * T_TOK + m0;
    const u16* B = Ball + (size_t)e * HID * DMODEL;

    const u16* ap[4];
    const u16* bp[4];
#pragma unroll
    for (int it = 0; it < 4; ++it) {
        int row = it * 32 + (tid >> 3);
        int gs = (tid & 7) ^ (row & 7);
        int id = mylist[row];
        int arow = (MODE == 0) ? (id >> 1) : id;
        ap[it] = Asrc + (size_t)arow * K + gs * 8;
        bp[it] = B + (size_t)(n0 + row) * K + gs * 8;
    }

    const int wm = (w >> 1) * 64;
    const int wn = (w & 1) * 64;
    const int quad = lane >> 4;
    const int lrow = lane & 15;

    f32x4 acc[4][4];
#pragma unroll
    for (int i = 0; i < 4; ++i)
#pragma unroll
        for (int j = 0; j < 4; ++j) acc[i][j] = f32x4{0.f, 0.f, 0.f, 0.f};

    for (int kt = 0; kt < NKT; ++kt) {
#pragma unroll
        for (int it = 0; it < 4; ++it)
            gl2lds16(ap[it] + kt * 64, &As[(it * 256 + w * 64) * 8]);
#pragma unroll
        for (int it = 0; it < 4; ++it)
            gl2lds16(bp[it] + kt * 64, &Bs[(it * 256 + w * 64) * 8]);
        __syncthreads();  // drain staging
#pragma unroll
        for (int s = 0; s < 2; ++s) {
            const int q = s * 4 + quad;
            bf16x8 af[4], bfr[4];
#pragma unroll
            for (int i = 0; i < 4; ++i) {
                int ra = wm + i * 16 + lrow;
                int rb = wn + i * 16 + lrow;
                af[i]  = *(const bf16x8*)&As[ra * 64 + (q ^ (ra & 7)) * 8];
                bfr[i] = *(const bf16x8*)&Bs[rb * 64 + (q ^ (rb & 7)) * 8];
            }
#pragma unroll
            for (int i = 0; i < 4; ++i)
#pragma unroll
                for (int j = 0; j < 4; ++j)
                    acc[i][j] = __builtin_amdgcn_mfma_f32_16x16x32_bf16(
                        af[i], bfr[j], acc[i][j], 0, 0, 0);
        }
        __syncthreads();  // protect LDS before next stage
    }

    // epilogue: C/D mapping col = lane&15, row = (lane>>4)*4 + reg
#pragma unroll
    for (int i = 0; i < 4; ++i) {
        int mbase = wm + i * 16 + (lane >> 4) * 4;
        int ids[4];
        float ww[4];
#pragma unroll
        for (int r = 0; r < 4; ++r) {
            ids[r] = mylist[mbase + r];
            if (MODE == 0) ww[r] = w2[ids[r]];
        }
#pragma unroll
        for (int j = 0; j < 4; ++j) {
            int n = n0 + wn + j * 16 + (lane & 15);
#pragma unroll
            for (int r = 0; r < 4; ++r) {
                float v = acc[i][j][r];
                if (MODE == 0) {
                    v = (v > 0.f) ? v * v * ww[r] : 0.f;
                    Hout[(size_t)ids[r] * HID + n] = f2bf(v);
                } else {
                    if (ids[r] != DUMP_ID)
                        atomicAdd(&Cout[(size_t)(ids[r] >> 1) * DMODEL + n], v);
                }
            }
        }
    }
}

// ---------------------------------------------------------------------------
extern "C" void kernel_launch(void* const* d_in, const int* in_sizes, int n_in,
                              void* d_out, int out_size, void* d_ws, size_t ws_size,
                              hipStream_t stream) {
    const float* x      = (const float*)d_in[0];
    const float* gate_w = (const float*)d_in[1];
    const float* w_up   = (const float*)d_in[2];
    const float* w_down = (const float*)d_in[3];
    const float* bias   = (const float*)d_in[4];
    float* out = (float*)d_out;

    // workspace layout (16B aligned chunks)
    char* p = (char*)d_ws;
    int* counts = (int*)p;                 p += 256;
    int* list   = (int*)p;                 p += NEXP * T_TOK * 4;
    float* w2   = (float*)p;               p += 4104 * 4;
    unsigned int* selpack = (unsigned int*)p;  p += T_TOK * 4;
    u16* xb  = (u16*)p;  p += (size_t)(T_TOK + 1) * DMODEL * 2;
    u16* wub = (u16*)p;  p += (size_t)NEXP * HID * DMODEL * 2;
    u16* wdb = (u16*)p;  p += (size_t)NEXP * HID * DMODEL * 2;
    u16* h   = (u16*)p;  p += (size_t)(2 * T_TOK + 1) * HID * 2;

    // 0. zero output (down-GEMM accumulates into it)
    hipMemsetAsync(d_out, 0, (size_t)out_size * sizeof(float), stream);

    // 1. fused: weight->bf16 conversion + router scores + dump-row init
    fused_pre<<<NB_CONV + 256 + 1, 256, 0, stream>>>(
        (const float4*)w_up, (const float4*)w_down,
        (ushort4*)wub, (ushort4*)wdb,
        (const float4*)x, (const float4*)gate_w, bias,
        (ushort4*)xb, selpack, w2,
        (unsigned int*)(xb + (size_t)T_TOK * DMODEL));

    // 2. deterministic list build (no global atomics)
    build_lists<<<NEXP, 256, 0, stream>>>(selpack, counts, list);

    // 3. up-GEMM: h = bf16( w2 * relu(x @ Wu^T)^2 )
    moe_gemm<0><<<16 * (HID / 128) * NEXP, 256, 0, stream>>>(
        xb, list, counts, wub, w2, h, nullptr);

    // 4. down-GEMM + combine: out[t] += h[id] @ Wd^T
    moe_gemm<1><<<16 * (DMODEL / 128) * NEXP, 256, 0, stream>>>(
        h, list, counts, wdb, w2, nullptr, out);
}